// Round 5
// baseline (2161.251 us; speedup 1.0000x reference)
//
#include <hip/hip_runtime.h>
#include <hip/hip_bf16.h>
#include <cstdint>

// ---------------------------------------------------------------------------
// RNN_CRF: BiLSTM(B=32,T=256,E=256,H=512) -> linear(K=32) -> CRF viterbi
// Persistent flag-synced LSTM. This rev:
//  - k_wprep preconverts weights to bf16 hi/lo MFMA frags (kills in-loop
//    rematerialized f32 loads + split2 VALU; weights pinned via asm loads)
//  - R3 overlap order restored: spin -> h loads -> x-proj MFMAs (hide LLC lat)
//  - tid-linear hstage (no LDS bank conflicts), coalesced wave0 publish
//  - no barrier after publish (vmcnt orders flag); per-wave flag subsets
// ---------------------------------------------------------------------------

typedef __attribute__((ext_vector_type(8)))  short          s8v;
typedef __attribute__((ext_vector_type(8)))  __bf16         bf8v;
typedef __attribute__((ext_vector_type(16))) float          f32x16;
typedef __attribute__((ext_vector_type(4)))  float          f32x4v;
typedef __attribute__((ext_vector_type(4)))  unsigned int   u32x4;
typedef __attribute__((ext_vector_type(8)))  unsigned short u16x8;
typedef __attribute__((ext_vector_type(4)))  unsigned short u16x4;

// ---- mfma shim: gfx950 builtin may take v8bf16 or v8i16 -------------------
template <typename V>
static __device__ inline auto mfma_try(V a, V b, f32x16 c, int)
    -> decltype(__builtin_amdgcn_mfma_f32_32x32x16_bf16(a, b, c, 0, 0, 0)) {
  return __builtin_amdgcn_mfma_f32_32x32x16_bf16(a, b, c, 0, 0, 0);
}
template <typename V>
static __device__ inline f32x16 mfma_try(V a, V b, f32x16 c, long) {
  return __builtin_amdgcn_mfma_f32_32x32x16_bf16(
      __builtin_bit_cast(bf8v, a), __builtin_bit_cast(bf8v, b), c, 0, 0, 0);
}
static __device__ inline f32x16 mfma32(u32x4 a, u32x4 b, f32x16 c) {
  return mfma_try(__builtin_bit_cast(s8v, a), __builtin_bit_cast(s8v, b), c, 0);
}

// ---- bf16 split helpers ---------------------------------------------------
static __device__ inline unsigned short bf_trunc(float x) {
  return (unsigned short)(__builtin_bit_cast(unsigned int, x) >> 16);
}
static __device__ inline float bf_up(unsigned short h) {
  return __builtin_bit_cast(float, ((unsigned int)h) << 16);
}
static __device__ inline void split2(float x, unsigned short& hi, unsigned short& lo) {
  hi = bf_trunc(x);
  lo = bf_trunc(x - bf_up(hi));
}
static __device__ inline float sigmoidf_(float x) { return 1.0f / (1.0f + __expf(-x)); }
static __device__ inline float tanhf_(float x) {
  float ax = fabsf(x);
  float e  = __expf(-2.0f * ax);
  float t  = (1.0f - e) / (1.0f + e);
  return x < 0.0f ? -t : t;
}

// ---- raw memory ops (untracked by compiler; manual waitcnt discipline) ----
static __device__ inline u32x4 ld16(const void* p) {           // cached
  u32x4 r;
  asm volatile("global_load_dwordx4 %0, %1, off" : "=v"(r) : "v"(p) : "memory");
  return r;
}
static __device__ inline u32x4 ld_cohere16(const void* p) {    // LLC-coherent
  u32x4 r;
  asm volatile("global_load_dwordx4 %0, %1, off sc0 sc1" : "=v"(r) : "v"(p) : "memory");
  return r;
}
static __device__ inline void st_cohere16(void* p, u32x4 v) {  // wide write-through
  asm volatile("global_store_dwordx4 %0, %1, off sc0 sc1" :: "v"(p), "v"(v) : "memory");
}
static __device__ inline void st_cohere4(void* p, int v) {
  asm volatile("global_store_dword %0, %1, off sc0 sc1" :: "v"(p), "v"(v) : "memory");
}
#define WAITVM(N)                                              \
  do {                                                         \
    asm volatile("s_waitcnt vmcnt(" #N ")" ::: "memory");      \
    __builtin_amdgcn_sched_barrier(0);                         \
  } while (0)

// ===========================================================================
// K1: embedding gather -> x split to bf16 hi/lo. row = t*32+b, 256 elems.
// ===========================================================================
__global__ void k_embed(const int* __restrict__ sent, const float* __restrict__ emb,
                        unsigned short* __restrict__ xhi, unsigned short* __restrict__ xlo) {
  int row  = blockIdx.x * 4 + (threadIdx.x >> 6);
  int lane = threadIdx.x & 63;
  int t = row >> 5, b = row & 31;
  int tok = sent[b * 256 + t];
  const f32x4v v = *(const f32x4v*)(emb + (long)tok * 256 + lane * 4);
  u16x4 h4, l4;
#pragma unroll
  for (int i = 0; i < 4; ++i) {
    unsigned short h, l;
    split2(v[i], h, l);
    h4[i] = h; l4[i] = l;
  }
  *(u16x4*)(xhi + (long)row * 256 + lane * 4) = h4;
  *(u16x4*)(xlo + (long)row * 256 + lane * 4) = l4;
}

// ===========================================================================
// K2: weight preconvert. One thread per (dir,b64,w,frag f,lane) -> one u16x8.
// f: 0..7 wbh[k8], 8..15 wbl[k8], 16..19 wih_h[k4], 20..23 wih_l[k4].
// Linear layout == thread index g; k_lstm loads frag f at
//   wfrag + ((((dir*64+b64)*4+w)*24 + f)*64 + lane)*8.
// ===========================================================================
__global__ void k_wprep(const float* __restrict__ Whh_f, const float* __restrict__ Whh_b,
                        const float* __restrict__ Wih_f, const float* __restrict__ Wih_b,
                        unsigned short* __restrict__ wfrag) {
  unsigned int g = blockIdx.x * 256 + threadIdx.x;   // [0, 786432)
  int lane = g & 63;
  unsigned int r = g >> 6;
  int f = r % 24; r /= 24;
  int w = r & 3;  r >>= 2;
  int b64 = r & 63;
  int dir = (int)(r >> 6);
  int n = lane & 31, kh = lane >> 5;
  int wrow = ((n >> 3) << 9) + (b64 << 3) + (n & 7);
  const float* src;
  bool hi;
  if (f < 16) {
    int k8 = f & 7; hi = (f < 8);
    src = (dir ? Whh_b : Whh_f) + (long)wrow * 512 + (w << 7) + (k8 << 4) + (kh << 3);
  } else {
    int k4 = (f - 16) & 3; hi = (f < 20);
    src = (dir ? Wih_b : Wih_f) + (long)wrow * 256 + (w << 6) + (k4 << 4) + (kh << 3);
  }
  f32x4v a = *(const f32x4v*)src, b2 = *(const f32x4v*)(src + 4);
  u16x8 o;
#pragma unroll
  for (int i = 0; i < 8; ++i) {
    float v = (i < 4) ? a[i] : b2[i - 4];
    unsigned short h, l; split2(v, h, l);
    o[i] = hi ? h : l;
  }
  *(u16x8*)(wfrag + (long)g * 8) = o;
}

// ===========================================================================
// K3: persistent bidirectional LSTM. 128 blocks: dir=blk>>6, b64=blk&63.
// hist[dir][slot 0..256][b64][512 shorts] (hi 256 | lo 256).
// Loop: per-wave flag spin -> issue 16 h loads -> x-proj MFMAs (x prefetched
// last iter, hides h LLC latency) -> staged vmcnt recurrent MFMAs -> zp ->
// gates -> x prefetch -> hstage -> wave0 wide store + vmcnt(0) + flag.
// ===========================================================================
__global__ __launch_bounds__(256, 1) void k_lstm(
    const float* __restrict__ b_f, const float* __restrict__ b_b,
    const float* __restrict__ h0,  const float* __restrict__ c0,
    const unsigned short* __restrict__ xhi, const unsigned short* __restrict__ xlo,
    const unsigned short* __restrict__ wfrag,
    unsigned short* __restrict__ hist, int* __restrict__ flags) {
  const int tid = threadIdx.x, lane = tid & 63, w = tid >> 6;
  const int blk = blockIdx.x, dir = blk >> 6, b64 = blk & 63;
  const float* bias = dir ? b_b : b_f;

  __shared__ float zp[4][32][33];
  __shared__ __align__(16) unsigned short hstage[512];  // hi 256 | lo 256

  const int kh = lane >> 5;   // k half within 16-wide K step
  const int m  = lane & 31;   // A-frag row == batch

  // ---- pin weight frags in registers (asm loads can't be rematerialized)
  const unsigned short* wf =
      wfrag + (((long)(dir * 64 + b64) * 4 + w) * 24) * 64 * 8;
  u32x4 wbh[8], wbl[8], wihh[4], wihl[4];
#pragma unroll
  for (int k8 = 0; k8 < 8; ++k8) wbh[k8] = ld16(wf + ((k8)*64 + lane) * 8);
#pragma unroll
  for (int k8 = 0; k8 < 8; ++k8) wbl[k8] = ld16(wf + ((8 + k8) * 64 + lane) * 8);
#pragma unroll
  for (int k4 = 0; k4 < 4; ++k4) wihh[k4] = ld16(wf + ((16 + k4) * 64 + lane) * 8);
#pragma unroll
  for (int k4 = 0; k4 < 4; ++k4) wihl[k4] = ld16(wf + ((20 + k4) * 64 + lane) * 8);
  WAITVM(0);

  // ---- gate-thread state: gb = tid>>3, gi = tid&7  (hstage index == tid)
  const int gb = tid >> 3;
  const int gi = tid & 7;
  const int gidx = (b64 << 3) + gi;
  float c = c0[(dir * 32 + gb) * 512 + gidx];
  float bias4[4];
#pragma unroll
  for (int g = 0; g < 4; ++g) bias4[g] = bias[(g << 9) + gidx];

  // ---- prefetch x for step 0 (stays in regs through publish)
  u32x4 xah_[4], xal_[4];
  {
    const int t0 = dir ? 255 : 0;
#pragma unroll
    for (int k4 = 0; k4 < 4; ++k4) {
      long ro = (long)(t0 * 32 + m) * 256 + (w << 6) + (k4 << 4) + (kh << 3);
      xah_[k4] = ld16(xhi + ro);
      xal_[k4] = ld16(xlo + ro);
    }
  }

  // ---- publish h_0 into slot 0
  {
    float hv = h0[(dir * 32 + gb) * 512 + gidx];
    unsigned short hh, ll; split2(hv, hh, ll);
    hstage[tid] = hh;
    hstage[256 + tid] = ll;
  }
  __syncthreads();
  if (w == 0) {
    u32x4 v = ((const u32x4*)hstage)[lane];
    char* dst = (char*)hist + (((long)dir * 257 + 0) * 64 + b64) * 1024 + lane * 16;
    st_cohere16(dst, v);
    WAITVM(0);  // drains wave0's store (and its x prefetch)
    if (lane == 0) st_cohere4(flags + dir * 64 + b64, 1);
  }
  // no barrier needed: waves are gated by the flag spin below.

  for (int step = 0; step < 256; ++step) {
    // (1) per-wave spin: wave w consumes h only from blocks [w*16, w*16+16)
    {
      const int* fl = flags + dir * 64 + (w << 4);
      const int tgt = step + 1;
      while (true) {
        int fv = __hip_atomic_load(fl + (lane & 15), __ATOMIC_RELAXED,
                                   __HIP_MEMORY_SCOPE_AGENT);
        if (__all(fv >= tgt)) break;
      }
    }

    // (2) issue 16 h loads (LLC) from slot `step`
    const unsigned short* hb = hist + (((long)dir * 257 + step) * 64) * 512;
    u32x4 ah_[8], al_[8];
#pragma unroll
    for (int k8 = 0; k8 < 8; ++k8) {
      int bs = (w << 4) + (k8 << 1) + kh;
      ah_[k8] = ld_cohere16(hb + bs * 512 + m * 8);
      al_[k8] = ld_cohere16(hb + bs * 512 + 256 + m * 8);
    }

    // (3) x-proj MFMAs while h loads fly. WAITVM(16): waits only for the x
    // prefetch (issued before the h loads; for wave0 it's already drained).
    WAITVM(16);
    f32x16 acc0 = (f32x16)0.0f, acc1 = (f32x16)0.0f;
#pragma unroll
    for (int k4 = 0; k4 < 4; ++k4) {
      if (k4 & 1) {
        acc1 = mfma32(xah_[k4], wihh[k4], acc1);
        acc0 = mfma32(xah_[k4], wihl[k4], acc0);
        acc1 = mfma32(xal_[k4], wihh[k4], acc1);
      } else {
        acc0 = mfma32(xah_[k4], wihh[k4], acc0);
        acc1 = mfma32(xah_[k4], wihl[k4], acc1);
        acc0 = mfma32(xal_[k4], wihh[k4], acc0);
      }
    }

    // (4) recurrent MFMAs, staged on vmcnt
    WAITVM(8);
#pragma unroll
    for (int k8 = 0; k8 < 4; ++k8) {
      if (k8 & 1) {
        acc1 = mfma32(ah_[k8], wbh[k8], acc1);
        acc0 = mfma32(ah_[k8], wbl[k8], acc0);
        acc1 = mfma32(al_[k8], wbh[k8], acc1);
      } else {
        acc0 = mfma32(ah_[k8], wbh[k8], acc0);
        acc1 = mfma32(ah_[k8], wbl[k8], acc1);
        acc0 = mfma32(al_[k8], wbh[k8], acc0);
      }
    }
    WAITVM(0);
#pragma unroll
    for (int k8 = 4; k8 < 8; ++k8) {
      if (k8 & 1) {
        acc1 = mfma32(ah_[k8], wbh[k8], acc1);
        acc0 = mfma32(ah_[k8], wbl[k8], acc0);
        acc1 = mfma32(al_[k8], wbh[k8], acc1);
      } else {
        acc0 = mfma32(ah_[k8], wbh[k8], acc0);
        acc1 = mfma32(ah_[k8], wbl[k8], acc1);
        acc0 = mfma32(al_[k8], wbh[k8], acc0);
      }
    }

    // (5) partial z to LDS: C row = (reg&3)+8*(reg>>2)+4*kh (batch), col = n
    const int n = lane & 31;
#pragma unroll
    for (int r = 0; r < 16; ++r) {
      int mr = (r & 3) + ((r >> 2) << 3) + (kh << 2);
      zp[w][mr][n] = acc0[r] + acc1[r];
    }
    __syncthreads();

    // (6) gate math
    float z[4];
#pragma unroll
    for (int g = 0; g < 4; ++g)
      z[g] = zp[0][gb][g * 8 + gi] + zp[1][gb][g * 8 + gi] +
             zp[2][gb][g * 8 + gi] + zp[3][gb][g * 8 + gi] + bias4[g];
    float ig = sigmoidf_(z[0]);
    float fg = sigmoidf_(z[1]);
    float gg = tanhf_(z[2]);
    float og = sigmoidf_(z[3]);
    c = fg * c + ig * gg;
    float nh = og * tanhf_(c);
    unsigned short hh, ll; split2(nh, hh, ll);

    // (7) prefetch x for next step (completes during publish + next spin)
    if (step < 255) {
      const int tn = dir ? (254 - step) : (step + 1);
#pragma unroll
      for (int k4 = 0; k4 < 4; ++k4) {
        long ro = (long)(tn * 32 + m) * 256 + (w << 6) + (k4 << 4) + (kh << 3);
        xah_[k4] = ld16(xhi + ro);
        xal_[k4] = ld16(xlo + ro);
      }
    }

    // (8) publish h into slot step+1 (tid-linear hstage: conflict-free)
    hstage[tid] = hh;
    hstage[256 + tid] = ll;
    __syncthreads();
    if (w == 0) {
      u32x4 v = ((const u32x4*)hstage)[lane];
      char* dst =
          (char*)hist + (((long)dir * 257 + step + 1) * 64 + b64) * 1024 + lane * 16;
      st_cohere16(dst, v);
      WAITVM(0);  // order data-ack before flag (wave0-local)
      if (lane == 0) st_cohere4(flags + dir * 64 + b64, step + 2);
    }
    // no trailing barrier: next-iter spin gates every wave that needs our h.
  }
}

// ===========================================================================
// K4: feats[b,t,k] = concat(hf,hb) @ Wout^T + bout. One block per t.
// h_f[t] = hist[0][t+1], h_b[t] = hist[1][256-t].
// ===========================================================================
__global__ __launch_bounds__(256, 1) void k_feats(
    const unsigned short* __restrict__ hist,
    const float* __restrict__ Wout, const float* __restrict__ bout,
    float* __restrict__ feats) {
  const int tid = threadIdx.x, lane = tid & 63, w = tid >> 6;
  const int t = blockIdx.x;
  __shared__ float zp[4][32][33];
  const int n = lane & 31, kh = lane >> 5;
  const int dirw = w >> 1, koff = (w & 1) * 256;

  u16x8 bh[16], bl[16];
#pragma unroll
  for (int k = 0; k < 16; ++k) {
    const float* src = Wout + (long)n * 1024 + dirw * 512 + koff + (k << 4) + (kh << 3);
    f32x4v a = *(const f32x4v*)src, b2 = *(const f32x4v*)(src + 4);
    u16x8 hh, ll;
#pragma unroll
    for (int i = 0; i < 8; ++i) {
      float v = (i < 4) ? a[i] : b2[i - 4];
      unsigned short x1, x2; split2(v, x1, x2);
      hh[i] = x1; ll[i] = x2;
    }
    bh[k] = hh; bl[k] = ll;
  }

  const int m = lane & 31;  // batch
  const int slot = dirw ? (256 - t) : (t + 1);
  const unsigned short* base = hist + (((long)dirw * 257 + slot) * 64) * 512;
  f32x16 acc = (f32x16)0.0f;
#pragma unroll
  for (int k = 0; k < 16; ++k) {
    int ksrc = koff + (k << 4) + (kh << 3);
    int bs = ksrc >> 3;
    u32x4 ah = *(const u32x4*)(base + bs * 512 + m * 8);
    u32x4 al = *(const u32x4*)(base + bs * 512 + 256 + m * 8);
    acc = mfma32(ah, __builtin_bit_cast(u32x4, bh[k]), acc);
    acc = mfma32(ah, __builtin_bit_cast(u32x4, bl[k]), acc);
    acc = mfma32(al, __builtin_bit_cast(u32x4, bh[k]), acc);
  }
#pragma unroll
  for (int r = 0; r < 16; ++r) {
    int mr = (r & 3) + ((r >> 2) << 3) + (kh << 2);
    zp[w][mr][n] = acc[r];
  }
  __syncthreads();

  const int k = tid & 31, mb = tid >> 5;
#pragma unroll
  for (int q = 0; q < 4; ++q) {
    int mm = mb * 4 + q;  // batch
    float v = zp[0][mm][k] + zp[1][mm][k] + zp[2][mm][k] + zp[3][mm][k] + bout[k];
    feats[((long)mm * 256 + t) * 32 + k] = v;
  }
}

// ===========================================================================
// K5: Viterbi. One wave per batch, barrier-free scan.
// ===========================================================================
__global__ __launch_bounds__(64, 1) void k_viterbi(const float* __restrict__ feats,
                                                   const float* __restrict__ trans,
                                                   float* __restrict__ out) {
  const int b = blockIdx.x, lane = threadIdx.x;
  __shared__ __align__(16) float fsh[256][32];
  __shared__ unsigned char bp[256][32];

  const float* fb = feats + (long)b * 8192;
#pragma unroll 4
  for (int i = lane; i < 2048; i += 64)
    ((f32x4v*)&fsh[0][0])[i] = ((const f32x4v*)fb)[i];

  float tr_[32];
  float vl = 0.0f;
  if (lane < 32) {
#pragma unroll
    for (int p = 0; p < 32; ++p) tr_[p] = trans[lane * 32 + p];
    vl = (lane == 30) ? 0.0f : -10000.0f;
  }
  __syncthreads();

  if (lane < 32) {
    for (int t = 0; t < 256; ++t) {
      float best = -3.0e38f; int arg = 0;
#pragma unroll
      for (int p = 0; p < 32; ++p) {
        float vp = __shfl(vl, p, 32);
        float sc = vp + tr_[p];
        if (sc > best) { best = sc; arg = p; }  // strict > keeps FIRST max
      }
      vl = best + fsh[t][lane];
      bp[t][lane] = (unsigned char)arg;
    }
    float tv = vl + trans[31 * 32 + lane];
    int ta = lane;
#pragma unroll
    for (int d = 16; d; d >>= 1) {
      float ov = __shfl_xor(tv, d, 32);
      int   oa = __shfl_xor(ta, d, 32);
      if (ov > tv || (ov == tv && oa < ta)) { tv = ov; ta = oa; }
    }
    if (lane == 0) {
      out[b] = tv;
      int tag = ta;
      for (int t = 255; t >= 0; --t) {
        out[32 + (long)b * 256 + t] = (float)tag;
        tag = bp[t][tag];
      }
    }
  }
}

// ===========================================================================
extern "C" void kernel_launch(void* const* d_in, const int* in_sizes, int n_in,
                              void* d_out, int out_size, void* d_ws, size_t ws_size,
                              hipStream_t stream) {
  (void)in_sizes; (void)n_in; (void)out_size; (void)ws_size;
  const int*   sent  = (const int*)d_in[0];
  const float* emb   = (const float*)d_in[1];
  const float* Wih_f = (const float*)d_in[2];
  const float* Whh_f = (const float*)d_in[3];
  const float* b_f   = (const float*)d_in[4];
  const float* Wih_b = (const float*)d_in[5];
  const float* Whh_b = (const float*)d_in[6];
  const float* b_b   = (const float*)d_in[7];
  const float* Wout  = (const float*)d_in[8];
  const float* bout  = (const float*)d_in[9];
  const float* trans = (const float*)d_in[10];
  const float* h0    = (const float*)d_in[11];
  const float* c0    = (const float*)d_in[12];
  float* out = (float*)d_out;

  char* ws = (char*)d_ws;
  unsigned short* xhi   = (unsigned short*)(ws + 0);              // 4 MB
  unsigned short* xlo   = (unsigned short*)(ws + (4ull << 20));   // 4 MB
  unsigned short* hist  = (unsigned short*)(ws + (8ull << 20));   // ~32.1 MB
  unsigned short* wfrag = (unsigned short*)(ws + (41ull << 20));  // 12.6 MB
  float*          fts   = (float*)(ws + (54ull << 20));           // 1 MB
  int*            flg   = (int*)(ws + (55ull << 20) + (512ull << 10)); // 512 B

  hipMemsetAsync(flg, 0, 128 * sizeof(int), stream);
  k_embed<<<2048, 256, 0, stream>>>(sent, emb, xhi, xlo);
  k_wprep<<<3072, 256, 0, stream>>>(Whh_f, Whh_b, Wih_f, Wih_b, wfrag);
  k_lstm<<<128, 256, 0, stream>>>(b_f, b_b, h0, c0, xhi, xlo, wfrag, hist, flg);
  k_feats<<<256, 256, 0, stream>>>(hist, Wout, bout, fts);
  k_viterbi<<<32, 64, 0, stream>>>(fts, trans, out);
}